// Round 1
// baseline (365.875 us; speedup 1.0000x reference)
//
#include <hip/hip_runtime.h>

#define GENE_N  200000
#define BATCH   200000
#define EMBED   128
#define BM      64
#define THREADS 512
#define LDS_STRIDE 136   // bf16 elems per LDS row: 128 + 8 pad (272B -> conflict-free-ish)

typedef __attribute__((ext_vector_type(8))) short bf16x8;
typedef __attribute__((ext_vector_type(4))) float f32x4;

static __device__ __forceinline__ short f2bf(float f) {
    unsigned u = __builtin_bit_cast(unsigned, f);
    unsigned r = (u + 0x7fffu + ((u >> 16) & 1u)) >> 16;   // RNE
    return (short)(r & 0xffffu);
}
static __device__ __forceinline__ float fsigmoid(float x) {
    return 1.0f / (1.0f + __expf(-x));
}
static __device__ __forceinline__ float ftanh(float x) {
    float t = 1.0f - 2.0f / (__expf(2.0f * fabsf(x)) + 1.0f);
    return copysignf(t, x);
}

__global__ __launch_bounds__(THREADS, 2)
void hetagg_kernel(const float* __restrict__ gene_feat,
                   const float* __restrict__ cell_feat,
                   const float* __restrict__ gWf, const float* __restrict__ gbf,
                   const float* __restrict__ gWb, const float* __restrict__ gbb,
                   const float* __restrict__ cWf, const float* __restrict__ cbf,
                   const float* __restrict__ cWb, const float* __restrict__ cbb,
                   const int* __restrict__ c_ids, const int* __restrict__ p_ids,
                   const int* __restrict__ n_ids, float* __restrict__ out,
                   int gene_blocks, int cell_blocks)
{
    __shared__ short A_lds[BM * LDS_STRIDE];

    const int  bid     = blockIdx.x;
    const bool is_gene = (bid < gene_blocks);
    const int  tid     = threadIdx.x;
    const int  wid     = tid >> 6;
    const int  lane    = tid & 63;
    const int  lgrp    = lane >> 4;   // 0..3
    const int  lcol    = lane & 15;   // 0..15
    const int  dir     = wid >> 2;    // 0 fwd, 1 bwd
    const int  jt      = wid & 3;     // which 16-wide j block
    const int  j       = jt * 16 + lcol;  // output idx within direction [0,64)

    const float* feat = is_gene ? gene_feat : cell_feat;
    const float* W    = is_gene ? (dir ? gWb : gWf) : (dir ? cWb : cWf);
    const float* Bv   = is_gene ? (dir ? gbb : gbf) : (dir ? cbb : cbf);

    // torch gate order i,f,g,o -> rows i:[0,64) g:[128,192) o:[192,256); f unused (c0=0)
    const float bias_i = Bv[j];
    const float bias_g = Bv[128 + j];
    const float bias_o = Bv[192 + j];

    // B fragments held in registers for the whole kernel.
    // B[k][n] = W[gate_base+ j(n)][k]; lane: col=lcol, k = s*32 + lgrp*8 + r
    bf16x8 bfrag[3][4];
    {
        const int gate_base[3] = {0, 128, 192};
#pragma unroll
        for (int q = 0; q < 3; ++q) {
            const float* wrow = W + (size_t)(gate_base[q] + j) * EMBED;
#pragma unroll
            for (int s = 0; s < 4; ++s) {
                const int k0 = s * 32 + lgrp * 8;
                float4 w0 = *(const float4*)(wrow + k0);
                float4 w1 = *(const float4*)(wrow + k0 + 4);
                bf16x8 b;
                b[0] = f2bf(w0.x); b[1] = f2bf(w0.y);
                b[2] = f2bf(w0.z); b[3] = f2bf(w0.w);
                b[4] = f2bf(w1.x); b[5] = f2bf(w1.y);
                b[6] = f2bf(w1.z); b[7] = f2bf(w1.w);
                bfrag[q][s] = b;
            }
        }
    }

    const int myb    = is_gene ? bid : (bid - gene_blocks);
    const int nb     = is_gene ? gene_blocks : cell_blocks;
    const int ntiles = is_gene ? (BATCH / BM) : (2 * BATCH / BM);

    const int r0 = tid >> 5;   // 0..15 (row within pass)
    const int cc = tid & 31;   // float4 column within row

    const f32x4 zero = {0.f, 0.f, 0.f, 0.f};

    for (int tile = myb; tile < ntiles; tile += nb) {
        const int base = tile * BM;
        __syncthreads();   // protect LDS from previous iteration's readers

        // ---- gather 64 rows, cvt f32->bf16, stage to LDS ----
#pragma unroll
        for (int p = 0; p < 4; ++p) {
            const int r    = r0 + p * 16;
            const int grow = base + r;
            int id;
            if (is_gene)            id = c_ids[grow];
            else if (grow < BATCH)  id = p_ids[grow] - GENE_N;
            else                    id = n_ids[grow - BATCH] - GENE_N;
            const float4 v = ((const float4*)(feat + (size_t)id * EMBED))[cc];
            short4 sv;
            sv.x = f2bf(v.x); sv.y = f2bf(v.y);
            sv.z = f2bf(v.z); sv.w = f2bf(v.w);
            *(short4*)&A_lds[r * LDS_STRIDE + cc * 4] = sv;
        }
        __syncthreads();

        // ---- MFMA: gates = X @ Wpack^T ----
        f32x4 acc[4][3];
#pragma unroll
        for (int mt = 0; mt < 4; ++mt)
#pragma unroll
            for (int q = 0; q < 3; ++q)
                acc[mt][q] = zero;

#pragma unroll
        for (int s = 0; s < 4; ++s) {
#pragma unroll
            for (int mt = 0; mt < 4; ++mt) {
                const int m = mt * 16 + lcol;
                bf16x8 a = *(const bf16x8*)&A_lds[m * LDS_STRIDE + s * 32 + lgrp * 8];
                acc[mt][0] = __builtin_amdgcn_mfma_f32_16x16x32_bf16(a, bfrag[0][s], acc[mt][0], 0, 0, 0);
                acc[mt][1] = __builtin_amdgcn_mfma_f32_16x16x32_bf16(a, bfrag[1][s], acc[mt][1], 0, 0, 0);
                acc[mt][2] = __builtin_amdgcn_mfma_f32_16x16x32_bf16(a, bfrag[2][s], acc[mt][2], 0, 0, 0);
            }
        }

        // ---- epilogue: bias + LSTM activations, store ----
        // C/D layout (verified): value r of acc sits at row=(lane>>4)*4+r, col=lane&15
#pragma unroll
        for (int mt = 0; mt < 4; ++mt) {
#pragma unroll
            for (int r = 0; r < 4; ++r) {
                const float gi = acc[mt][0][r] + bias_i;
                const float gg = acc[mt][1][r] + bias_g;
                const float go = acc[mt][2][r] + bias_o;
                const float cv = fsigmoid(gi) * ftanh(gg);
                const float h  = fsigmoid(go) * ftanh(cv);
                const int row  = base + mt * 16 + lgrp * 4 + r;
                const size_t orow = (size_t)(is_gene ? row : (BATCH + row));
                out[orow * 128 + dir * 64 + j] = h;
            }
        }
    }
}

extern "C" void kernel_launch(void* const* d_in, const int* in_sizes, int n_in,
                              void* d_out, int out_size, void* d_ws, size_t ws_size,
                              hipStream_t stream)
{
    const float* gene_feat = (const float*)d_in[0];
    const float* cell_feat = (const float*)d_in[1];
    const float* gWf = (const float*)d_in[2];
    const float* gbf = (const float*)d_in[3];
    const float* gWb = (const float*)d_in[4];
    const float* gbb = (const float*)d_in[5];
    const float* cWf = (const float*)d_in[6];
    const float* cbf = (const float*)d_in[7];
    const float* cWb = (const float*)d_in[8];
    const float* cbb = (const float*)d_in[9];
    const int* c_ids = (const int*)d_in[10];
    const int* p_ids = (const int*)d_in[11];
    const int* n_ids = (const int*)d_in[12];
    float* out = (float*)d_out;

    const int gene_blocks = 640;   // 3125 tiles of 64 rows
    const int cell_blocks = 1280;  // 6250 tiles (p then n, shared weights)
    dim3 grid(gene_blocks + cell_blocks);
    dim3 block(THREADS);
    hipLaunchKernelGGL(hetagg_kernel, grid, block, 0, stream,
                       gene_feat, cell_feat, gWf, gbf, gWb, gbb,
                       cWf, cbf, cWb, cbb, c_ids, p_ids, n_ids, out,
                       gene_blocks, cell_blocks);
}

// Round 2
// 275.224 us; speedup vs baseline: 1.3294x; 1.3294x over previous
//
#include <hip/hip_runtime.h>

#define GENE_N  200000
#define BATCH   200000
#define EMBED   128
#define BM      64
#define THREADS 512
#define LDS_STRIDE 136   // bf16 elems per LDS row: 128 + 8 pad

typedef __attribute__((ext_vector_type(8))) short bf16x8;
typedef __attribute__((ext_vector_type(4))) float f32x4;

static __device__ __forceinline__ short f2bf(float f) {
    unsigned u = __builtin_bit_cast(unsigned, f);
    unsigned r = (u + 0x7fffu + ((u >> 16) & 1u)) >> 16;   // RNE
    return (short)(r & 0xffffu);
}
static __device__ __forceinline__ float fsigmoid(float x) {
    return 1.0f / (1.0f + __expf(-x));
}
static __device__ __forceinline__ float ftanh(float x) {
    float t = 1.0f - 2.0f / (__expf(2.0f * fabsf(x)) + 1.0f);
    return copysignf(t, x);
}

__global__ __launch_bounds__(THREADS, 2)
void hetagg_kernel(const float* __restrict__ gene_feat,
                   const float* __restrict__ cell_feat,
                   const float* __restrict__ gWf, const float* __restrict__ gbf,
                   const float* __restrict__ gWb, const float* __restrict__ gbb,
                   const float* __restrict__ cWf, const float* __restrict__ cbf,
                   const float* __restrict__ cWb, const float* __restrict__ cbb,
                   const int* __restrict__ c_ids, const int* __restrict__ p_ids,
                   const int* __restrict__ n_ids, float* __restrict__ out,
                   int gene_blocks, int cell_blocks)
{
    __shared__ short A_lds[BM * LDS_STRIDE];

    const int  bid     = blockIdx.x;
    const bool is_gene = (bid < gene_blocks);
    const int  tid     = threadIdx.x;
    const int  wid     = tid >> 6;
    const int  lane    = tid & 63;
    const int  lgrp    = lane >> 4;   // 0..3
    const int  lcol    = lane & 15;   // 0..15
    const int  dir     = wid >> 2;    // 0 fwd, 1 bwd
    const int  jt      = wid & 3;     // 16-wide j block
    const int  j       = jt * 16 + lcol;

    const float* feat = is_gene ? gene_feat : cell_feat;
    const float* W    = is_gene ? (dir ? gWb : gWf) : (dir ? cWb : cWf);
    const float* Bv   = is_gene ? (dir ? gbb : gbf) : (dir ? cbb : cbf);

    // gate order i,f,g,o; f unused (c0 = 0)
    const float bias_i = Bv[j];
    const float bias_g = Bv[128 + j];
    const float bias_o = Bv[192 + j];

    // B fragments in registers for the whole kernel
    bf16x8 bfrag[3][4];
    {
        const int gate_base[3] = {0, 128, 192};
#pragma unroll
        for (int q = 0; q < 3; ++q) {
            const float* wrow = W + (size_t)(gate_base[q] + j) * EMBED;
#pragma unroll
            for (int s = 0; s < 4; ++s) {
                const int k0 = s * 32 + lgrp * 8;
                float4 w0 = *(const float4*)(wrow + k0);
                float4 w1 = *(const float4*)(wrow + k0 + 4);
                bf16x8 b;
                b[0] = f2bf(w0.x); b[1] = f2bf(w0.y);
                b[2] = f2bf(w0.z); b[3] = f2bf(w0.w);
                b[4] = f2bf(w1.x); b[5] = f2bf(w1.y);
                b[6] = f2bf(w1.z); b[7] = f2bf(w1.w);
                bfrag[q][s] = b;
            }
        }
    }

    const int myb    = is_gene ? bid : (bid - gene_blocks);
    const int nb     = is_gene ? gene_blocks : cell_blocks;
    const int ntiles = is_gene ? (BATCH / BM) : (2 * BATCH / BM);

    const int r0 = tid >> 5;   // 0..15
    const int cc = tid & 31;   // float4 col within row

    const f32x4 zero = {0.f, 0.f, 0.f, 0.f};

#define FETCH_ID(grow) (is_gene ? c_ids[(grow)] \
                       : ((grow) < BATCH ? p_ids[(grow)] - GENE_N \
                                         : n_ids[(grow) - BATCH] - GENE_N))

    // ---- pipeline prologue: rows(t) in flight, ids(t+1) in flight ----
    int t = myb;
    float4 rv[4];   // prefetched rows of tile t (quarter-rows per thread)
    int    idn[4];  // ids of tile t+nb
    {
        int id0[4];
#pragma unroll
        for (int p = 0; p < 4; ++p) id0[p] = FETCH_ID(t * BM + r0 + p * 16);
#pragma unroll
        for (int p = 0; p < 4; ++p)
            rv[p] = ((const float4*)(feat + (size_t)id0[p] * EMBED))[cc];
        const int t2 = t + nb;
#pragma unroll
        for (int p = 0; p < 4; ++p)
            idn[p] = (t2 < ntiles) ? FETCH_ID(t2 * BM + r0 + p * 16) : 0;
    }

    for (; t < ntiles; t += nb) {
        const int  base = t * BM;
        const bool hn   = (t + nb < ntiles);

        // protect LDS: all waves done reading previous tile
        __builtin_amdgcn_s_barrier();

        // ---- stage prefetched rows: cvt f32->bf16 -> LDS ----
#pragma unroll
        for (int p = 0; p < 4; ++p) {
            short4 sv;
            sv.x = f2bf(rv[p].x); sv.y = f2bf(rv[p].y);
            sv.z = f2bf(rv[p].z); sv.w = f2bf(rv[p].w);
            *(short4*)&A_lds[(r0 + p * 16) * LDS_STRIDE + cc * 4] = sv;
        }
        asm volatile("s_waitcnt lgkmcnt(0)" ::: "memory");
        __builtin_amdgcn_s_barrier();

        // ---- issue next tile's gathers (fly during MFMA + epilogue) ----
        if (hn) {
            const int tn = t + nb;
#pragma unroll
            for (int p = 0; p < 4; ++p)
                rv[p] = ((const float4*)(feat + (size_t)idn[p] * EMBED))[cc];
            const int t3 = tn + nb;
            if (t3 < ntiles) {
#pragma unroll
                for (int p = 0; p < 4; ++p)
                    idn[p] = FETCH_ID(t3 * BM + r0 + p * 16);
            }
        }

        // ---- MFMA ----
        f32x4 acc[4][3];
#pragma unroll
        for (int mt = 0; mt < 4; ++mt)
#pragma unroll
            for (int q = 0; q < 3; ++q)
                acc[mt][q] = zero;

#pragma unroll
        for (int s = 0; s < 4; ++s) {
#pragma unroll
            for (int mt = 0; mt < 4; ++mt) {
                const int m = mt * 16 + lcol;
                bf16x8 a = *(const bf16x8*)&A_lds[m * LDS_STRIDE + s * 32 + lgrp * 8];
                acc[mt][0] = __builtin_amdgcn_mfma_f32_16x16x32_bf16(a, bfrag[0][s], acc[mt][0], 0, 0, 0);
                acc[mt][1] = __builtin_amdgcn_mfma_f32_16x16x32_bf16(a, bfrag[1][s], acc[mt][1], 0, 0, 0);
                acc[mt][2] = __builtin_amdgcn_mfma_f32_16x16x32_bf16(a, bfrag[2][s], acc[mt][2], 0, 0, 0);
            }
        }

        // ---- epilogue: bias + LSTM activations, store ----
#pragma unroll
        for (int mt = 0; mt < 4; ++mt) {
#pragma unroll
            for (int r = 0; r < 4; ++r) {
                const float gi = acc[mt][0][r] + bias_i;
                const float gg = acc[mt][1][r] + bias_g;
                const float go = acc[mt][2][r] + bias_o;
                const float cv = fsigmoid(gi) * ftanh(gg);
                const float h  = fsigmoid(go) * ftanh(cv);
                const int row  = base + mt * 16 + lgrp * 4 + r;
                const size_t orow = (size_t)(is_gene ? row : (BATCH + row));
                out[orow * 128 + dir * 64 + j] = h;
            }
        }
    }
#undef FETCH_ID
}

extern "C" void kernel_launch(void* const* d_in, const int* in_sizes, int n_in,
                              void* d_out, int out_size, void* d_ws, size_t ws_size,
                              hipStream_t stream)
{
    const float* gene_feat = (const float*)d_in[0];
    const float* cell_feat = (const float*)d_in[1];
    const float* gWf = (const float*)d_in[2];
    const float* gbf = (const float*)d_in[3];
    const float* gWb = (const float*)d_in[4];
    const float* gbb = (const float*)d_in[5];
    const float* cWf = (const float*)d_in[6];
    const float* cbf = (const float*)d_in[7];
    const float* cWb = (const float*)d_in[8];
    const float* cbb = (const float*)d_in[9];
    const int* c_ids = (const int*)d_in[10];
    const int* p_ids = (const int*)d_in[11];
    const int* n_ids = (const int*)d_in[12];
    float* out = (float*)d_out;

    const int gene_blocks = 320;   // 3125 tiles -> ~9.8 tiles/block
    const int cell_blocks = 640;   // 6250 tiles -> ~9.8 tiles/block
    dim3 grid(gene_blocks + cell_blocks);
    dim3 block(THREADS);
    hipLaunchKernelGGL(hetagg_kernel, grid, block, 0, stream,
                       gene_feat, cell_feat, gWf, gbf, gWb, gbb,
                       cWf, cbf, cWb, cbb, c_ids, p_ids, n_ids, out,
                       gene_blocks, cell_blocks);
}